// Round 1
// 4531.008 us; speedup vs baseline: 1.0853x; 1.0853x over previous
//
#include <hip/hip_runtime.h>
#include <stdint.h>

// SimpleRNN on MI355X — persistent kernel, plain launch (R4).
//
// R1 (release+threadfence, cached data): PASS, 23.4 us/step — fences flush a
//   DIRTY L2 every step + post-inv refetch storm (FETCH 607 MB).
// R2 (all-relaxed, sc1-bypass data): FAIL absmax 0.34 — h-stores and flag
//   store can take different fabric channels to different LLC banks; only the
//   release wbl2-drain orders them. Also relaxed-everything let the compiler
//   reorder staging loads above the poll.
// R3 (sc1 data + real release/acquire, clean L2): PASS, 9.4 us/step.
// R4 = R3 minus the removable coherence costs:
//   - DROP the acquire buffer_inv (per-step 4MB L2 tag walk). Safe because no
//     agent-visible address is ever cache-resident before its final value is
//     at the LLC: all out[] stores are sc1, poll/xp loads are sc1, and every
//     staged address (row t-1) is read at exactly one step and written only
//     at step t-1. Ordering vs the poll = in-order per-wave issue + control
//     dep + __syncthreads (full compiler+HW barrier). Compiler-only fence.
//   - Staging loads become PLAIN CACHED float4: each staged line enters an
//     L2 only after some wg passed its flag check (=> h already in LLC =>
//     fill is fresh), is shared by the 4 same-group wgs on that XCD
//     (blk%8 round-robin => group g has slices j, j%8==xcd), and is never
//     read again => no staleness, 4x less LLC read traffic (8MB->2MB/step),
//     L2-latency for 3/4 wgs.
//   - xp load hoisted ABOVE the poll: wg-private (this wg wrote it in phase
//     1), so its LLC latency hides under the flag wait.
//   INVARIANTS that must not be broken: all global STORES stay sc1 (a dirty
//   out[] line in L2 would be stale-written-back over newer LLC data AND
//   makes the release wbl2 expensive); xp/poll LOADS stay sc1 (a cached xp
//   line of row t would be stale for step t+1's staging).
//
// B=64, T=512, D=128, H=1024, fp32. 8 batch-groups x 32 col-slices = 256 wgs
// (1/CU). Wh[:,slice] register-resident (float4 w4[32] = 128 VGPRs/thread).
// Flags: monotonic exact-match 'f-t<=1' -> 0xAA-poison safe, no init/reset.

#define Bb 64
#define Tt 512
#define Dd 128
#define Hh 1024
#define NG 8      // batch groups
#define RPG 8     // rows per group
#define NS 32     // col slices per group
#define CPS 32    // cols per slice
#define HROW 1152 // h_lds row stride (floats): 32 chunks * 36
#define KCS 36    // chunk stride (32 data + 4 pad) -> conflict-free reads

typedef unsigned long long u64;

__device__ __forceinline__ float agent_load_f32(const float* p) {
  return __hip_atomic_load(p, __ATOMIC_RELAXED, __HIP_MEMORY_SCOPE_AGENT);
}
__device__ __forceinline__ void agent_store_f32(float* p, float v) {
  __hip_atomic_store(p, v, __ATOMIC_RELAXED, __HIP_MEMORY_SCOPE_AGENT);
}

__global__ __launch_bounds__(256, 1) void rnn_persist(
    const float* __restrict__ x, const float* __restrict__ Wx,
    const float* __restrict__ Wh, const float* __restrict__ bias,
    float* __restrict__ out, uint32_t* __restrict__ flags)
{
  __shared__ __align__(16) float h_lds[RPG * HROW];   // 36 KB
  __shared__ __align__(16) float red2[4 * RPG * CPS]; // 4 KB

  const int tid = threadIdx.x;
  const int blk = blockIdx.x;
  const int j = blk & (NS - 1);
  const int g = blk >> 5;
  const int rowbase = g * RPG;
  const int colbase = j * CPS;

  // ---------------- Phase 1: xp = x @ Wx + b -------------------------------
  {
    const int cx = tid & 31;   // col within slice
    const int rx = tid >> 5;   // row within group
    float wx[Dd];              // Wx column, register-stationary
#pragma unroll
    for (int d = 0; d < Dd; ++d)
      wx[d] = Wx[d * Hh + colbase + cx];
    const float bb = bias[colbase + cx];

    float* x_lds = h_lds;          // reuse as [8][132]
    const int srow = tid >> 5;
    const int sd4 = (tid & 31) * 4;

    for (int tt = 0; tt < Tt; ++tt) {
      float4 xv = *(const float4*)(x + (size_t)(rowbase + srow) * Tt * Dd +
                                   (size_t)tt * Dd + sd4);
      __syncthreads();
      *(float4*)(x_lds + srow * 132 + sd4) = xv;
      __syncthreads();
      float a = 0.f;
#pragma unroll
      for (int d4 = 0; d4 < 32; ++d4) {
        float4 v = *(const float4*)(x_lds + rx * 132 + 4 * d4);
        a += v.x * wx[4 * d4 + 0];
        a += v.y * wx[4 * d4 + 1];
        a += v.z * wx[4 * d4 + 2];
        a += v.w * wx[4 * d4 + 3];
      }
      // sc1 store: out[] lines must NEVER be dirty in L2 (single-copy rule)
      agent_store_f32(out + (size_t)(rowbase + rx) * Tt * Hh +
                          (size_t)tt * Hh + colbase + cx,
                      a + bb);
    }
  }

  // ---------------- Load Wh slice into registers ---------------------------
  const int cg = tid & 7;    // col-quad within slice (4 cols)
  const int kc = tid >> 3;   // k-chunk 0..31 (32 k each)
  float4 w4[32];             // Wh[32kc..32kc+32) x 4 cols  (128 regs)
  {
    const float* wp = Wh + (size_t)(32 * kc) * Hh + colbase + 4 * cg;
#pragma unroll
    for (int k = 0; k < 32; ++k)
      w4[k] = *(const float4*)(wp + (size_t)k * Hh);
  }

  const int rr = tid >> 5;
  const int cc = tid & 31;
  const size_t obase0 = (size_t)(rowbase + rr) * Tt * Hh + colbase + cc;
  uint32_t* gflags = flags + g * NS;

  // staging address (constant across t): cols [c4, c4+4) of each group row,
  // chunk-padded LDS slot lof
  const int c4 = 4 * tid;        // 0..1020
  const int lof = (c4 >> 5) * KCS + (c4 & 31);

  // ---------------- Recurrence -------------------------------------------
  for (int t = 0; t < Tt; ++t) {
    float hres;
    if (t == 0) {
      hres = tanhf(agent_load_f32(out + obase0));  // h0=0 -> h_1 = tanh(xp_0)
    } else {
      // wg-private xp: issue BEFORE the wait so its latency hides under the
      // poll. Must stay sc1 (a cached row-t line would be stale for t+1).
      const float xp_val = agent_load_f32(out + obase0 + (size_t)t * Hh);

      // wait for all 32 slices of h_{t-1} (flag t; producer may be at t+1)
      if (tid < 64) {
        if (tid < NS) {
          const uint32_t want = (uint32_t)t;
          while (true) {
            uint32_t f = __hip_atomic_load(&gflags[tid], __ATOMIC_RELAXED,
                                           __HIP_MEMORY_SCOPE_AGENT);
            if ((uint32_t)(f - want) <= 1u) break;
            __builtin_amdgcn_s_sleep(1);
          }
        }
        // NO buffer_inv: compiler-only ordering. HW freshness holds because
        // no agent-visible line is cached anywhere before its final value
        // reached the LLC (all stores sc1; staged rows read at one step only).
        asm volatile("" ::: "memory");
      }
      __syncthreads();   // other waves' loads cannot cross this barrier

      // stage h_{t-1} (8 rows x 1024) into chunk-padded LDS layout.
      // PLAIN cached loads: first requester on an XCD fills L2 (fresh, since
      // every fill happens after a flag-pass), 3 group-mates on that XCD hit.
      {
        const float* hsrc = out + (size_t)rowbase * Tt * Hh +
                            (size_t)(t - 1) * Hh + c4;
        float4 hv[RPG];
#pragma unroll
        for (int q = 0; q < RPG; ++q)
          hv[q] = *(const float4*)(hsrc + (size_t)q * Tt * Hh);
#pragma unroll
        for (int q = 0; q < RPG; ++q)
          *(float4*)(h_lds + q * HROW + lof) = hv[q];
      }
      __syncthreads();

      // GEMM partials: this thread's 32-k window x 4 cols x 8 rows
      float4 acc[RPG];
#pragma unroll
      for (int r = 0; r < RPG; ++r) acc[r] = make_float4(0.f, 0.f, 0.f, 0.f);
#pragma unroll
      for (int r = 0; r < RPG; ++r) {
        const float* hrow = h_lds + r * HROW + kc * KCS;
#pragma unroll
        for (int k4 = 0; k4 < 8; ++k4) {
          float4 hv = *(const float4*)(hrow + 4 * k4);
          float4 w0 = w4[4 * k4 + 0], w1 = w4[4 * k4 + 1];
          float4 w2 = w4[4 * k4 + 2], w3 = w4[4 * k4 + 3];
          acc[r].x += hv.x * w0.x; acc[r].y += hv.x * w0.y;
          acc[r].z += hv.x * w0.z; acc[r].w += hv.x * w0.w;
          acc[r].x += hv.y * w1.x; acc[r].y += hv.y * w1.y;
          acc[r].z += hv.y * w1.z; acc[r].w += hv.y * w1.w;
          acc[r].x += hv.z * w2.x; acc[r].y += hv.z * w2.y;
          acc[r].z += hv.z * w2.z; acc[r].w += hv.z * w2.w;
          acc[r].x += hv.w * w3.x; acc[r].y += hv.w * w3.y;
          acc[r].z += hv.w * w3.z; acc[r].w += hv.w * w3.w;
        }
      }

      // reduce over k-chunks: in-wave butterfly (kc bits are lane bits 3..5)
#pragma unroll
      for (int m = 8; m <= 32; m <<= 1) {
#pragma unroll
        for (int r = 0; r < RPG; ++r) {
          acc[r].x += __shfl_xor(acc[r].x, m, 64);
          acc[r].y += __shfl_xor(acc[r].y, m, 64);
          acc[r].z += __shfl_xor(acc[r].z, m, 64);
          acc[r].w += __shfl_xor(acc[r].w, m, 64);
        }
      }
      if ((tid & 63) < 8) {          // one lane per col-quad per wave
        const int w = tid >> 6;
#pragma unroll
        for (int r = 0; r < RPG; ++r)
          *(float4*)(&red2[(w * RPG + r) * CPS + 4 * cg]) = acc[r];
      }
      __syncthreads();
      float s = red2[(0 * RPG + rr) * CPS + cc] +
                red2[(1 * RPG + rr) * CPS + cc] +
                red2[(2 * RPG + rr) * CPS + cc] +
                red2[(3 * RPG + rr) * CPS + cc];
      hres = tanhf(s + xp_val);
    }

    agent_store_f32(out + obase0 + (size_t)t * Hh, hres);  // xp slot -> h_t
    __syncthreads();   // all waves' h stores drained (vmcnt(0)) before flag
    if (tid == 0)
      __hip_atomic_store(&gflags[j], (uint32_t)(t + 1), __ATOMIC_RELEASE,
                         __HIP_MEMORY_SCOPE_AGENT);  // wbl2 walks a CLEAN L2
  }
}

extern "C" void kernel_launch(void* const* d_in, const int* in_sizes, int n_in,
                              void* d_out, int out_size, void* d_ws,
                              size_t ws_size, hipStream_t stream) {
  const float* x  = (const float*)d_in[0];
  const float* Wx = (const float*)d_in[1];
  const float* Wh = (const float*)d_in[2];
  const float* bv = (const float*)d_in[3];
  float* out = (float*)d_out;
  uint32_t* flags = (uint32_t*)d_ws;  // 8*32 u32 = 1 KB; 0xAA poison is safe

  rnn_persist<<<dim3(NG * NS), dim3(256), 0, stream>>>(x, Wx, Wh, bv, out,
                                                       flags);
}

// Round 2
// 3218.065 us; speedup vs baseline: 1.5280x; 1.4080x over previous
//
#include <hip/hip_runtime.h>
#include <stdint.h>

// SimpleRNN on MI355X — persistent kernel, plain launch (R5).
//
// R1 (release+threadfence, cached data): PASS, 23.4 us/step — dirty-L2 wbl2.
// R2 (all-relaxed, sc1 data): FAIL — release wbl2-drain is what orders h
//   stores vs flag store when they cross XCDs.
// R3 (sc1 data + release/acquire, clean L2): PASS, 9.4 us/step.
// R4 (drop acquire-inv, cached staging, hoisted xp): PASS, 8.85 us/step.
//   Lesson: no single fence dominates — EVERY sync edge (store ack, flag,
//   poll, staging) round-trips the LLC because groups span all 8 XCDs.
// R5 = XCD-LOCAL GROUPS. Blocks are dispatched round-robin across XCDs
//   (blk%8 = XCD, learn_hip m09), so grouping g=blk&7, j=blk>>3 puts each
//   group's 32 wgs on ONE XCD sharing ONE L2:
//   - h exchange entirely in local L2: plain write-through stores (vmcnt-ack
//     at barrier => in L2), plain staging loads hit the just-written lines.
//   - NO wbl2: release edge = barrier's vmcnt(0) + flag store. Flags go via
//     LLC (agent sc1 both sides) — the only LLC hop per step.
//   - SAFETY: mapping is not a contract. Each wg reads HW_REG_XCC_ID and
//     publishes a mismatch bit in its flag (flag=((t+1)<<1)|mm). Consumers
//     OR the bits they already poll -> grp_mm. Any misplacement => whole
//     group falls back to the proven R3 protocol (sc1 h-stores, release
//     fence wbl2 over clean L2, sc1 staging). t=0 is conservative fallback.
//   - L1 hazard fix: staging SKIPS the own-slice chunk; each wg writes its
//     own h values into h_lds from registers each step. No out[] line is
//     ever read twice by one CU => no stale-L1 path; xp/phase-1/t0 loads
//     can be plain cached.
//
// B=64, T=512, D=128, H=1024, fp32. 8 groups x 32 slices = 256 wgs (1/CU).
// Wh[:,slice] register-resident (float4 w4[32] = 128 VGPRs/thread).
// Flags monotonic, 0xAA-poison safe ((poison>>1)-t never <=1), no init.

#define Bb 64
#define Tt 512
#define Dd 128
#define Hh 1024
#define NG 8      // batch groups
#define RPG 8     // rows per group
#define NS 32     // col slices per group
#define CPS 32    // cols per slice
#define HROW 1152 // h_lds row stride (floats): 32 chunks * 36
#define KCS 36    // chunk stride (32 data + 4 pad) -> conflict-free reads

typedef unsigned long long u64;

__device__ __forceinline__ float2 agent_load_f32x2(const float* p) {
  union { u64 u; float2 f; } c;
  c.u = __hip_atomic_load((const u64*)p, __ATOMIC_RELAXED,
                          __HIP_MEMORY_SCOPE_AGENT);
  return c.f;
}
__device__ __forceinline__ void agent_store_f32(float* p, float v) {
  __hip_atomic_store(p, v, __ATOMIC_RELAXED, __HIP_MEMORY_SCOPE_AGENT);
}

__global__ __launch_bounds__(256, 1) void rnn_persist(
    const float* __restrict__ x, const float* __restrict__ Wx,
    const float* __restrict__ Wh, const float* __restrict__ bias,
    float* __restrict__ out, uint32_t* __restrict__ flags)
{
  __shared__ __align__(16) float h_lds[RPG * HROW];   // 36 KB
  __shared__ __align__(16) float red2[4 * RPG * CPS]; // 4 KB
  __shared__ uint32_t sm_grp;

  const int tid = threadIdx.x;
  const int blk = blockIdx.x;
  const int g = blk & 7;        // group = nominal XCD (round-robin dispatch)
  const int j = blk >> 3;       // slice within group
  const int rowbase = g * RPG;
  const int colbase = j * CPS;

  uint32_t xcc;
  asm volatile("s_getreg_b32 %0, hwreg(HW_REG_XCC_ID)" : "=s"(xcc));
  const uint32_t my_mm = (xcc != (uint32_t)g) ? 1u : 0u;

  // ---------------- Phase 1: xp = x @ Wx + b (plain stores) ---------------
  {
    const int cx = tid & 31;   // col within slice
    const int rx = tid >> 5;   // row within group
    float wx[Dd];              // Wx column, register-stationary
#pragma unroll
    for (int d = 0; d < Dd; ++d)
      wx[d] = Wx[d * Hh + colbase + cx];
    const float bb = bias[colbase + cx];

    float* x_lds = h_lds;          // reuse as [8][132]
    const int srow = tid >> 5;
    const int sd4 = (tid & 31) * 4;

    for (int tt = 0; tt < Tt; ++tt) {
      float4 xv = *(const float4*)(x + (size_t)(rowbase + srow) * Tt * Dd +
                                   (size_t)tt * Dd + sd4);
      __syncthreads();
      *(float4*)(x_lds + srow * 132 + sd4) = xv;
      __syncthreads();
      float a = 0.f;
#pragma unroll
      for (int d4 = 0; d4 < 32; ++d4) {
        float4 v = *(const float4*)(x_lds + rx * 132 + 4 * d4);
        a += v.x * wx[4 * d4 + 0];
        a += v.y * wx[4 * d4 + 1];
        a += v.z * wx[4 * d4 + 2];
        a += v.w * wx[4 * d4 + 3];
      }
      // xp is only ever read back by THIS wg (own slice) -> plain store.
      out[(size_t)(rowbase + rx) * Tt * Hh + (size_t)tt * Hh + colbase + cx] =
          a + bb;
    }
  }

  __syncthreads();  // drain phase-1 LDS use + self store->load ordering

  // ---------------- Load Wh slice into registers ---------------------------
  const int cg = tid & 7;    // col-quad within slice (4 cols)
  const int kc = tid >> 3;   // k-chunk 0..31 (32 k each)
  float4 w4[32];             // Wh[32kc..32kc+32) x 4 cols  (128 regs)
  {
    const float* wp = Wh + (size_t)(32 * kc) * Hh + colbase + 4 * cg;
#pragma unroll
    for (int k = 0; k < 32; ++k)
      w4[k] = *(const float4*)(wp + (size_t)k * Hh);
  }

  const int rr = tid >> 5;
  const int cc = tid & 31;
  const size_t obase0 = (size_t)(rowbase + rr) * Tt * Hh + colbase + cc;
  uint32_t* gflags = flags + g * NS;

  const int c4 = 4 * tid;                      // staged cols [c4, c4+4)
  const int lof = (c4 >> 5) * KCS + (c4 & 31); // chunk-padded LDS slot
  const bool own_chunk = ((tid >> 3) == j);    // own-slice chunk: via LDS
  const int own_slot = rr * HROW + j * KCS + cc;

  uint32_t grp_mm = 1u;  // conservative until first poll

  // ---------------- Recurrence -------------------------------------------
  for (int t = 0; t < Tt; ++t) {
    float hres;
    if (t == 0) {
      hres = tanhf(out[obase0]);  // h0=0 -> h_1 = tanh(xp_0); self-written
    } else {
      // wg-private xp: plain cached, hoisted above the wait. Its L1 line
      // (own-slice cols of row t) is never read again by this CU.
      const float xp_val = out[obase0 + (size_t)t * Hh];

      // wait for all 32 slices of h_{t-1}: flag>>1 in {t, t+1}
      if (tid < 64) {
        uint32_t bit = 0;
        if (tid < NS) {
          const uint32_t want = (uint32_t)t;
          while (true) {
            uint32_t f = __hip_atomic_load(&gflags[tid], __ATOMIC_RELAXED,
                                           __HIP_MEMORY_SCOPE_AGENT);
            if ((uint32_t)((f >> 1) - want) <= 1u) { bit = f & 1u; break; }
            __builtin_amdgcn_s_sleep(1);
          }
        }
        uint32_t any = (uint32_t)__any((int)bit);
        if (tid == 0) sm_grp = any;
        asm volatile("" ::: "memory");
      }
      __syncthreads();   // ordering + publish sm_grp
      grp_mm = sm_grp;

      // stage h_{t-1} (8 rows x 1024) into LDS, skipping own chunk
      if (!own_chunk) {
        const float* hsrc = out + (size_t)rowbase * Tt * Hh +
                            (size_t)(t - 1) * Hh + c4;
        if (!grp_mm) {
          // XCD-local: plain loads hit the shared L2 (just written there)
          float4 hv[RPG];
#pragma unroll
          for (int q = 0; q < RPG; ++q)
            hv[q] = *(const float4*)(hsrc + (size_t)q * Tt * Hh);
#pragma unroll
          for (int q = 0; q < RPG; ++q)
            *(float4*)(h_lds + q * HROW + lof) = hv[q];
        } else {
          // fallback: R3 protocol, sc1 reads from LLC
          float2 lo[RPG], hi[RPG];
#pragma unroll
          for (int q = 0; q < RPG; ++q) {
            const float* p = hsrc + (size_t)q * Tt * Hh;
            lo[q] = agent_load_f32x2(p);
            hi[q] = agent_load_f32x2(p + 2);
          }
#pragma unroll
          for (int q = 0; q < RPG; ++q)
            *(float4*)(h_lds + q * HROW + lof) =
                make_float4(lo[q].x, lo[q].y, hi[q].x, hi[q].y);
        }
      }
      __syncthreads();

      // GEMM partials: this thread's 32-k window x 4 cols x 8 rows
      float4 acc[RPG];
#pragma unroll
      for (int r = 0; r < RPG; ++r) acc[r] = make_float4(0.f, 0.f, 0.f, 0.f);
#pragma unroll
      for (int r = 0; r < RPG; ++r) {
        const float* hrow = h_lds + r * HROW + kc * KCS;
#pragma unroll
        for (int k4 = 0; k4 < 8; ++k4) {
          float4 hv = *(const float4*)(hrow + 4 * k4);
          float4 w0 = w4[4 * k4 + 0], w1 = w4[4 * k4 + 1];
          float4 w2 = w4[4 * k4 + 2], w3 = w4[4 * k4 + 3];
          acc[r].x += hv.x * w0.x; acc[r].y += hv.x * w0.y;
          acc[r].z += hv.x * w0.z; acc[r].w += hv.x * w0.w;
          acc[r].x += hv.y * w1.x; acc[r].y += hv.y * w1.y;
          acc[r].z += hv.y * w1.z; acc[r].w += hv.y * w1.w;
          acc[r].x += hv.z * w2.x; acc[r].y += hv.z * w2.y;
          acc[r].z += hv.z * w2.z; acc[r].w += hv.z * w2.w;
          acc[r].x += hv.w * w3.x; acc[r].y += hv.w * w3.y;
          acc[r].z += hv.w * w3.z; acc[r].w += hv.w * w3.w;
        }
      }

      // reduce over k-chunks: in-wave butterfly (kc bits are lane bits 3..5)
#pragma unroll
      for (int m = 8; m <= 32; m <<= 1) {
#pragma unroll
        for (int r = 0; r < RPG; ++r) {
          acc[r].x += __shfl_xor(acc[r].x, m, 64);
          acc[r].y += __shfl_xor(acc[r].y, m, 64);
          acc[r].z += __shfl_xor(acc[r].z, m, 64);
          acc[r].w += __shfl_xor(acc[r].w, m, 64);
        }
      }
      if ((tid & 63) < 8) {          // one lane per col-quad per wave
        const int w = tid >> 6;
#pragma unroll
        for (int r = 0; r < RPG; ++r)
          *(float4*)(&red2[(w * RPG + r) * CPS + 4 * cg]) = acc[r];
      }
      __syncthreads();
      float s = red2[(0 * RPG + rr) * CPS + cc] +
                red2[(1 * RPG + rr) * CPS + cc] +
                red2[(2 * RPG + rr) * CPS + cc] +
                red2[(3 * RPG + rr) * CPS + cc];
      hres = tanhf(s + xp_val);
    }

    // own slice for next step goes straight to LDS (never re-read from out[])
    h_lds[own_slot] = hres;

    if (!grp_mm) {
      out[obase0 + (size_t)t * Hh] = hres;   // plain write-through -> local L2
    } else {
      agent_store_f32(out + obase0 + (size_t)t * Hh, hres);  // sc1 -> LLC
    }
    __syncthreads();   // vmcnt(0): all waves' h stores acked before flag
    if (tid == 0) {
      if (grp_mm)  // fallback release: wbl2 pushes h to LLC (L2 clean: sc1 h)
        __builtin_amdgcn_fence(__ATOMIC_RELEASE, "agent");
      __hip_atomic_store(&gflags[j], (uint32_t)(((t + 1) << 1) | my_mm),
                         __ATOMIC_RELAXED, __HIP_MEMORY_SCOPE_AGENT);
    }
  }
}

extern "C" void kernel_launch(void* const* d_in, const int* in_sizes, int n_in,
                              void* d_out, int out_size, void* d_ws,
                              size_t ws_size, hipStream_t stream) {
  const float* x  = (const float*)d_in[0];
  const float* Wx = (const float*)d_in[1];
  const float* Wh = (const float*)d_in[2];
  const float* bv = (const float*)d_in[3];
  float* out = (float*)d_out;
  uint32_t* flags = (uint32_t*)d_ws;  // 8*32 u32 = 1 KB; 0xAA poison is safe

  rnn_persist<<<dim3(NG * NS), dim3(256), 0, stream>>>(x, Wx, Wh, bv, out,
                                                       flags);
}

// Round 4
// 2811.922 us; speedup vs baseline: 1.7488x; 1.1444x over previous
//
#include <hip/hip_runtime.h>
#include <stdint.h>

// SimpleRNN on MI355X — persistent kernel, plain launch (R7).
//
// R1 cached+fences: 23.4 us/step. R2 all-relaxed: FAIL (release needs wbl2
//   when groups span XCDs). R3 sc1+acq/rel: 9.4. R4 -inv, cached staging:
//   8.85. R5 XCD-local groups (g=blk&7), plain h exchange via local L2,
//   flags via LLC, HW_REG_XCC_ID mismatch fallback: 6.3 us/step,
//   FETCH 663->93 MB (fast path confirmed engaged).
// R6: FAIL absmax 1.83 — changed two things at once (permlane16/32_swap
//   inline-asm butterfly with GUESSED semantics + local-TCC flag RMW poll).
//   Not diagnosable post-hoc. Reverted both.
// R7 = R5 + DS-pipe relief rebuilt on DOCUMENTED primitives only:
//   - Lane remap: cg = (tid>>3)&7, kc = (tid&7)|wave*8 — puts the k-chunk
//     reduction on lane bits 0-2, where classic gfx9 DPP covers every stage:
//     quad_perm:[1,0,3,2] (0xB1, xor1), quad_perm:[2,3,0,1] (0x4E, xor2),
//     row_half_mirror (0x141, pairs quads 0-3/4-7; valid because after two
//     stages every quad lane holds the quad sum). Same tree as __shfl_xor
//     up to commutative swaps -> bitwise-identical output (canary: absmax
//     must be exactly 0.00390625).
//   - Moves ~2300 cy/CU/step of ds_swizzle off the shared LDS pipe (which
//     also carries the GEMM ds_read_b128 stream) onto the VALU pipe.
//   - LDS conflict profile unchanged: 8 distinct ds_read addresses x 8-way
//     broadcast covering all 32 banks; red2 writers = (tid&7)==0, 8x16B.
//   - Wh prologue load is now scattered (one-time, ~us, accepted).
//   Flag protocol: EXACTLY R5 (agent relaxed poll + agent relaxed store;
//   mismatch fallback = agent release fence + sc1 data path).
//
// B=64, T=512, D=128, H=1024, fp32. 8 groups x 32 slices = 256 wgs (1/CU).
// Wh[:,slice] register-resident (float4 w4[32] = 128 VGPRs/thread).
// Flags monotonic, 0xAA-poison safe ((poison>>1)-t never <=1), no init.

#define Bb 64
#define Tt 512
#define Dd 128
#define Hh 1024
#define NG 8      // batch groups
#define RPG 8     // rows per group
#define NS 32     // col slices per group
#define CPS 32    // cols per slice
#define HROW 1152 // h_lds row stride (floats): 32 chunks * 36
#define KCS 36    // chunk stride (32 data + 4 pad) -> conflict-free reads

typedef unsigned long long u64;

__device__ __forceinline__ float2 agent_load_f32x2(const float* p) {
  union { u64 u; float2 f; } c;
  c.u = __hip_atomic_load((const u64*)p, __ATOMIC_RELAXED,
                          __HIP_MEMORY_SCOPE_AGENT);
  return c.f;
}
__device__ __forceinline__ void agent_store_f32(float* p, float v) {
  __hip_atomic_store(p, v, __ATOMIC_RELAXED, __HIP_MEMORY_SCOPE_AGENT);
}

// VALU-pipe butterfly stage: x + x[permuted lane], ctrl is a DPP control.
// 0xB1 = quad_perm:[1,0,3,2] (xor1), 0x4E = quad_perm:[2,3,0,1] (xor2),
// 0x141 = row_half_mirror (lane i <-> (i&~7)|(7-(i&7))).
template <int CTRL>
__device__ __forceinline__ float dpp_add(float x) {
  int p = __builtin_amdgcn_update_dpp(0, __float_as_int(x), CTRL, 0xf, 0xf,
                                      true);
  return x + __int_as_float(p);
}

__global__ __launch_bounds__(256, 1) void rnn_persist(
    const float* __restrict__ x, const float* __restrict__ Wx,
    const float* __restrict__ Wh, const float* __restrict__ bias,
    float* __restrict__ out, uint32_t* __restrict__ flags)
{
  __shared__ __align__(16) float h_lds[RPG * HROW];   // 36 KB
  __shared__ __align__(16) float red2[4 * RPG * CPS]; // 4 KB
  __shared__ uint32_t sm_grp;

  const int tid = threadIdx.x;
  const int blk = blockIdx.x;
  const int g = blk & 7;        // group = nominal XCD (round-robin dispatch)
  const int j = blk >> 3;       // slice within group
  const int rowbase = g * RPG;
  const int colbase = j * CPS;

  uint32_t xcc;
  asm volatile("s_getreg_b32 %0, hwreg(HW_REG_XCC_ID)" : "=s"(xcc));
  const uint32_t my_mm = (xcc != (uint32_t)g) ? 1u : 0u;

  // ---------------- Phase 1: xp = x @ Wx + b (plain stores) ---------------
  {
    const int cx = tid & 31;   // col within slice
    const int rx = tid >> 5;   // row within group
    float wx[Dd];              // Wx column, register-stationary
#pragma unroll
    for (int d = 0; d < Dd; ++d)
      wx[d] = Wx[d * Hh + colbase + cx];
    const float bb = bias[colbase + cx];

    float* x_lds = h_lds;          // reuse as [8][132]
    const int srow = tid >> 5;
    const int sd4 = (tid & 31) * 4;

    for (int tt = 0; tt < Tt; ++tt) {
      float4 xv = *(const float4*)(x + (size_t)(rowbase + srow) * Tt * Dd +
                                   (size_t)tt * Dd + sd4);
      __syncthreads();
      *(float4*)(x_lds + srow * 132 + sd4) = xv;
      __syncthreads();
      float a = 0.f;
#pragma unroll
      for (int d4 = 0; d4 < 32; ++d4) {
        float4 v = *(const float4*)(x_lds + rx * 132 + 4 * d4);
        a += v.x * wx[4 * d4 + 0];
        a += v.y * wx[4 * d4 + 1];
        a += v.z * wx[4 * d4 + 2];
        a += v.w * wx[4 * d4 + 3];
      }
      // xp is only ever read back by THIS wg (own slice) -> plain store.
      out[(size_t)(rowbase + rx) * Tt * Hh + (size_t)tt * Hh + colbase + cx] =
          a + bb;
    }
  }

  __syncthreads();  // drain phase-1 LDS use + self store->load ordering

  // ---------------- Load Wh slice into registers ---------------------------
  // Lane remap (R7): reduction axis on lane bits 0-2 so DPP covers it.
  const int cg = (tid >> 3) & 7;                 // col-quad within slice
  const int kc = (tid & 7) | ((tid >> 6) << 3);  // k-chunk 0..31
  float4 w4[32];             // Wh[32kc..32kc+32) x 4 cols  (128 regs)
  {
    const float* wp = Wh + (size_t)(32 * kc) * Hh + colbase + 4 * cg;
#pragma unroll
    for (int k = 0; k < 32; ++k)
      w4[k] = *(const float4*)(wp + (size_t)k * Hh);
  }

  const int rr = tid >> 5;
  const int cc = tid & 31;
  const size_t obase0 = (size_t)(rowbase + rr) * Tt * Hh + colbase + cc;
  uint32_t* gflags = flags + g * NS;

  const int c4 = 4 * tid;                      // staged cols [c4, c4+4)
  const int lof = (c4 >> 5) * KCS + (c4 & 31); // chunk-padded LDS slot
  const bool own_chunk = ((tid >> 3) == j);    // own-slice chunk: via LDS
  const int own_slot = rr * HROW + j * KCS + cc;

  uint32_t grp_mm = 1u;  // conservative until first poll

  // ---------------- Recurrence -------------------------------------------
  for (int t = 0; t < Tt; ++t) {
    float hres;
    if (t == 0) {
      hres = tanhf(out[obase0]);  // h0=0 -> h_1 = tanh(xp_0); self-written
    } else {
      // wg-private xp: plain cached, hoisted above the wait. Its L1 line
      // (own-slice cols of row t) is never read again by this CU.
      const float xp_val = out[obase0 + (size_t)t * Hh];

      // wait for all 32 slices of h_{t-1}: flag>>1 in {t, t+1}
      if (tid < 64) {
        uint32_t bit = 0;
        if (tid < NS) {
          const uint32_t want = (uint32_t)t;
          while (true) {
            uint32_t f = __hip_atomic_load(&gflags[tid], __ATOMIC_RELAXED,
                                           __HIP_MEMORY_SCOPE_AGENT);
            if ((uint32_t)((f >> 1) - want) <= 1u) { bit = f & 1u; break; }
            __builtin_amdgcn_s_sleep(1);
          }
        }
        uint32_t any = (uint32_t)__any((int)bit);
        if (tid == 0) sm_grp = any;
        asm volatile("" ::: "memory");
      }
      __syncthreads();   // ordering + publish sm_grp
      grp_mm = sm_grp;

      // stage h_{t-1} (8 rows x 1024) into LDS, skipping own chunk
      if (!own_chunk) {
        const float* hsrc = out + (size_t)rowbase * Tt * Hh +
                            (size_t)(t - 1) * Hh + c4;
        if (!grp_mm) {
          // XCD-local: plain loads hit the shared L2 (just written there)
          float4 hv[RPG];
#pragma unroll
          for (int q = 0; q < RPG; ++q)
            hv[q] = *(const float4*)(hsrc + (size_t)q * Tt * Hh);
#pragma unroll
          for (int q = 0; q < RPG; ++q)
            *(float4*)(h_lds + q * HROW + lof) = hv[q];
        } else {
          // fallback: R3 protocol, sc1 reads from LLC
          float2 lo[RPG], hi[RPG];
#pragma unroll
          for (int q = 0; q < RPG; ++q) {
            const float* p = hsrc + (size_t)q * Tt * Hh;
            lo[q] = agent_load_f32x2(p);
            hi[q] = agent_load_f32x2(p + 2);
          }
#pragma unroll
          for (int q = 0; q < RPG; ++q)
            *(float4*)(h_lds + q * HROW + lof) =
                make_float4(lo[q].x, lo[q].y, hi[q].x, hi[q].y);
        }
      }
      __syncthreads();

      // GEMM partials: this thread's 32-k window x 4 cols x 8 rows
      float4 acc[RPG];
#pragma unroll
      for (int r = 0; r < RPG; ++r) acc[r] = make_float4(0.f, 0.f, 0.f, 0.f);
#pragma unroll
      for (int r = 0; r < RPG; ++r) {
        const float* hrow = h_lds + r * HROW + kc * KCS;
#pragma unroll
        for (int k4 = 0; k4 < 8; ++k4) {
          float4 hv = *(const float4*)(hrow + 4 * k4);
          float4 w0 = w4[4 * k4 + 0], w1 = w4[4 * k4 + 1];
          float4 w2 = w4[4 * k4 + 2], w3 = w4[4 * k4 + 3];
          acc[r].x += hv.x * w0.x; acc[r].y += hv.x * w0.y;
          acc[r].z += hv.x * w0.z; acc[r].w += hv.x * w0.w;
          acc[r].x += hv.y * w1.x; acc[r].y += hv.y * w1.y;
          acc[r].z += hv.y * w1.z; acc[r].w += hv.y * w1.w;
          acc[r].x += hv.z * w2.x; acc[r].y += hv.z * w2.y;
          acc[r].z += hv.z * w2.z; acc[r].w += hv.z * w2.w;
          acc[r].x += hv.w * w3.x; acc[r].y += hv.w * w3.y;
          acc[r].z += hv.w * w3.z; acc[r].w += hv.w * w3.w;
        }
      }

      // reduce over in-wave kc (lane bits 0-2) on the VALU pipe via DPP.
      // Tree identical to the old __shfl_xor butterfly up to commutative
      // swaps -> bitwise-identical sums.
#pragma unroll
      for (int r = 0; r < RPG; ++r) {
        acc[r].x = dpp_add<0xB1>(acc[r].x);  acc[r].y = dpp_add<0xB1>(acc[r].y);
        acc[r].z = dpp_add<0xB1>(acc[r].z);  acc[r].w = dpp_add<0xB1>(acc[r].w);
      }
#pragma unroll
      for (int r = 0; r < RPG; ++r) {
        acc[r].x = dpp_add<0x4E>(acc[r].x);  acc[r].y = dpp_add<0x4E>(acc[r].y);
        acc[r].z = dpp_add<0x4E>(acc[r].z);  acc[r].w = dpp_add<0x4E>(acc[r].w);
      }
#pragma unroll
      for (int r = 0; r < RPG; ++r) {
        acc[r].x = dpp_add<0x141>(acc[r].x); acc[r].y = dpp_add<0x141>(acc[r].y);
        acc[r].z = dpp_add<0x141>(acc[r].z); acc[r].w = dpp_add<0x141>(acc[r].w);
      }
      if ((tid & 7) == 0) {          // one lane per col-quad per wave
        const int w = tid >> 6;
#pragma unroll
        for (int r = 0; r < RPG; ++r)
          *(float4*)(&red2[(w * RPG + r) * CPS + 4 * cg]) = acc[r];
      }
      __syncthreads();
      float s = red2[(0 * RPG + rr) * CPS + cc] +
                red2[(1 * RPG + rr) * CPS + cc] +
                red2[(2 * RPG + rr) * CPS + cc] +
                red2[(3 * RPG + rr) * CPS + cc];
      hres = tanhf(s + xp_val);
    }

    // own slice for next step goes straight to LDS (never re-read from out[])
    h_lds[own_slot] = hres;

    if (!grp_mm) {
      out[obase0 + (size_t)t * Hh] = hres;   // plain write-through -> local L2
    } else {
      agent_store_f32(out + obase0 + (size_t)t * Hh, hres);  // sc1 -> LLC
    }
    __syncthreads();   // vmcnt(0): all waves' h stores acked before flag
    if (tid == 0) {
      const uint32_t val = (uint32_t)(((t + 1) << 1) | my_mm);
      if (grp_mm)  // fallback release: wbl2 pushes h to LLC (L2 clean: sc1 h)
        __builtin_amdgcn_fence(__ATOMIC_RELEASE, "agent");
      __hip_atomic_store(&gflags[j], val, __ATOMIC_RELAXED,
                         __HIP_MEMORY_SCOPE_AGENT);
    }
  }
}

extern "C" void kernel_launch(void* const* d_in, const int* in_sizes, int n_in,
                              void* d_out, int out_size, void* d_ws,
                              size_t ws_size, hipStream_t stream) {
  const float* x  = (const float*)d_in[0];
  const float* Wx = (const float*)d_in[1];
  const float* Wh = (const float*)d_in[2];
  const float* bv = (const float*)d_in[3];
  float* out = (float*)d_out;
  uint32_t* flags = (uint32_t*)d_ws;  // 8*32 u32 = 1 KB; 0xAA poison is safe

  rnn_persist<<<dim3(NG * NS), dim3(256), 0, stream>>>(x, Wx, Wh, bv, out,
                                                       flags);
}